// Round 10
// baseline (124.964 us; speedup 1.0000x reference)
//
#include <hip/hip_runtime.h>

// LNSNet forward, R22: fc2 fused into fc1_mfma via DISTRIBUTED per-mt finisher.
// R20's failure was ONE block doing 65K serial agent-atomic loads; here the C
// rows of m-tile mt are complete once the 16 blocks bk in [16mt,16mt+15] (all
// ks x nt for that mt) have fired their atomics, so the 16th arriver of each
// mt finishes fc2 for its own 32 rows: 16 finisher blocks in parallel, 4096
// atomic loads each (16/thread), overlapped with other mts' MFMA. Removes the
// fc2k dispatch + drain + full C re-read (~3-4us). Same fence/atomic coherence
// mechanism R20 proved correct. conv12/prep frozen (R17/R21 forms).
// Standing: conv12 block split regresses (R18); SINGLE-block fc2 tails
// regress (R16/R20); atomic-vs-Cpart fc1 is a wash (R19b).

#define B 512
#define POS 676
#define ICP 36
#define P2SZ (64*12*12)
#define SCR 26
#define IMS 58                  // LDS image row stride (ushorts), odd dwords
#define IMCOPY (54 * IMS)       // 3132 ushorts per copy
#define PL_USH (POS * ICP)      // 24336 ushorts: pool1 in LDS
#define SCRATCH_USH 6656        // max(image 2*IMCOPY+96=6360, scr 8*832=6656)

typedef unsigned short ushort_t;
typedef ushort_t ushort4v __attribute__((ext_vector_type(4)));
typedef _Float16 f16x8 __attribute__((ext_vector_type(8)));
typedef float f32x4 __attribute__((ext_vector_type(4)));

__device__ __forceinline__ ushort_t f2h(float f) {
    union { _Float16 h; ushort_t u; } a; a.h = (_Float16)f; return a.u;
}
__device__ __forceinline__ float h2f(ushort_t u) {
    union { ushort_t u; _Float16 h; } a; a.u = u; return (float)a.h;
}

#define N_WR (64 * 9 * 32)
#define WR_BLOCKS 72
#define TR_BLOCKS 128
#define PREP_THREADS ((WR_BLOCKS + TR_BLOCKS) * 256)
#define FC1_BLOCKS 256

// ---------------- k0: conv2-weight reorder + fc1-W transpose + C/counter zero ----------------
__global__ __launch_bounds__(256) void prep(const float* __restrict__ c2w,
                                            const float* __restrict__ f1w,
                                            ushort_t* __restrict__ wr,
                                            ushort_t* __restrict__ wfb,
                                            float* __restrict__ C) {
    __shared__ float tr[64 * 145];          // 37,120 B (transpose branch only)
    int blk = blockIdx.x;
    int tid = threadIdx.x;

    // zero fc1 accumulator + 16 per-mt counters
    int gtid = blk * 256 + tid;
    for (int i = gtid; i < 512 * 128 + 16; i += PREP_THREADS) C[i] = 0.0f;

    if (blk < WR_BLOCKS) {
        int t = blk * 256 + tid;
        int ic  = t & 31;
        int tap = (t >> 5) % 9;
        int oc  = t / 288;
        wr[t] = f2h(c2w[oc * 288 + ic * 9 + tap]);
        return;
    }
    // ---- fc1 W transpose via LDS tile ----
    int n = blk - WR_BLOCKS;
    const float* src = f1w + (size_t)n * 9216;
#pragma unroll
    for (int i = 0; i < 36; ++i) {
        int idx = i * 256 + tid;
        int oc = idx / 144, pos = idx - oc * 144;
        tr[oc * 145 + pos] = src[idx];
    }
    __syncthreads();
    ushort_t* dst = wfb + (size_t)n * 9216;
#pragma unroll
    for (int i = 0; i < 36; ++i) {
        int idx = i * 256 + tid;
        int pos = idx >> 6, oc = idx & 63;
        dst[idx] = f2h(tr[oc * 145 + pos]);
    }
}

// ---------------- k12: fused conv1 -> pool1(LDS) -> conv2 -> pool2 (R17 form) ----------------
__global__ __launch_bounds__(512, 4) void conv12(const float* __restrict__ x,
                                                 const float* __restrict__ w1,
                                                 const float* __restrict__ bias1,
                                                 const ushort_t* __restrict__ wr,
                                                 const float* __restrict__ bias2,
                                                 ushort_t* __restrict__ pool2cl) {
    __shared__ ushort_t smem[PL_USH + SCRATCH_USH];   // 61,984 B -> 2 blocks/CU
    ushort_t* pl  = smem;            // pool1: [676 pos][36], cols 0..31 used
    ushort_t* img = smem + PL_USH;   // phase A image (2 col-shifted copies)

    int b   = blockIdx.x;
    int tid = threadIdx.x;
    int lane = tid & 63, wid = tid >> 6;        // 8 waves
    int quad = lane >> 4, lr = lane & 15;

    // ================= phase A: conv1 via MFMA =================
    for (int i = tid; i < 54; i += 512) {
        ushort_t* r0 = img + i * IMS;
        r0[54] = 0; r0[55] = 0; r0[56] = 0; r0[57] = 0;
        ushort_t* r1 = img + IMCOPY + i * IMS;
        r1[53] = 0; r1[54] = 0; r1[55] = 0; r1[56] = 0; r1[57] = 0;
    }
    if (tid < 96) img[2 * IMCOPY + tid] = 0;

    // stage image b: fp32 -> fp16 via float4 (2916 = 729 vec4; c==52 straddles)
    const float* xim = x + (size_t)b * 2916;
    for (int i = tid; i < 729; i += 512) {
        int e = i * 4;
        int r = e / 54, c = e - r * 54;        // c even
        float4 xv = *reinterpret_cast<const float4*>(&xim[e]);
        ushort_t h0 = f2h(xv.x), h1 = f2h(xv.y), h2 = f2h(xv.z), h3 = f2h(xv.w);
        if (c <= 50) {
            ushort_t* p0 = &img[r * IMS + c];
            p0[0] = h0; p0[1] = h1; p0[2] = h2; p0[3] = h3;
            ushort_t* p1 = &img[IMCOPY + r * IMS + c - 1];
            if (c > 0) p1[0] = h0;
            p1[1] = h1; p1[2] = h2; p1[3] = h3;
        } else {   // c == 52
            img[r * IMS + 52] = h0;
            img[r * IMS + 53] = h1;
            img[(r + 1) * IMS + 0] = h2;
            img[(r + 1) * IMS + 1] = h3;
            img[IMCOPY + r * IMS + 51] = h0;
            img[IMCOPY + r * IMS + 52] = h1;
            img[IMCOPY + (r + 1) * IMS + 0] = h3;
        }
    }

    // B-frags: w1[oc][ky=quad][kx=0..2], zeros elsewhere (incl quad==3)
    f16x8 bfrag[2];
#pragma unroll
    for (int n = 0; n < 2; ++n) {
        union { ushort_t u[8]; f16x8 v; } bu;
#pragma unroll
        for (int j = 0; j < 8; ++j) bu.u[j] = 0;
        if (quad < 3) {
            const float* wp = w1 + (n * 16 + lr) * 9 + quad * 3;
            bu.u[0] = f2h(wp[0]);
            bu.u[1] = f2h(wp[1]);
            bu.u[2] = f2h(wp[2]);
        }
        bfrag[n] = bu.v;
    }
    float bv0 = bias1[lr], bv1 = bias1[16 + lr];

    __syncthreads();

    int cbase = (lr & 1) ? (IMCOPY + lr - 1) : lr;

    for (int it = 0; it < 4; ++it) {
        int py = wid + it * 8;
        if (py >= 26) break;
        int y0 = 2 * py;
#pragma unroll
        for (int t = 0; t < 4; ++t) {
            int x0 = t * 16;
            int off0 = cbase + x0 + (y0 + quad) * IMS;
            int off1 = off0 + IMS;
            union { unsigned d[4]; f16x8 v; } a0, a1;
            a0.d[0] = *reinterpret_cast<const unsigned*>(&img[off0]);
            a0.d[1] = *reinterpret_cast<const unsigned*>(&img[off0 + 2]);
            a0.d[2] = a0.d[0]; a0.d[3] = a0.d[1];
            a1.d[0] = *reinterpret_cast<const unsigned*>(&img[off1]);
            a1.d[1] = *reinterpret_cast<const unsigned*>(&img[off1 + 2]);
            a1.d[2] = a1.d[0]; a1.d[3] = a1.d[1];

            f32x4 cA0 = (f32x4){0.f,0.f,0.f,0.f}, cA1 = cA0, cB0 = cA0, cB1 = cA0;
            cA0 = __builtin_amdgcn_mfma_f32_16x16x32_f16(a0.v, bfrag[0], cA0, 0, 0, 0);
            cA1 = __builtin_amdgcn_mfma_f32_16x16x32_f16(a0.v, bfrag[1], cA1, 0, 0, 0);
            cB0 = __builtin_amdgcn_mfma_f32_16x16x32_f16(a1.v, bfrag[0], cB0, 0, 0, 0);
            cB1 = __builtin_amdgcn_mfma_f32_16x16x32_f16(a1.v, bfrag[1], cB1, 0, 0, 0);

            if (t < 3 || quad == 0) {
                int px0 = t * 8 + quad * 2;
                float u0 = fmaxf(fmaxf(cA0[0], cA0[1]), fmaxf(cB0[0], cB0[1]));
                float u1 = fmaxf(fmaxf(cA0[2], cA0[3]), fmaxf(cB0[2], cB0[3]));
                float v0 = fmaxf(fmaxf(cA1[0], cA1[1]), fmaxf(cB1[0], cB1[1]));
                float v1 = fmaxf(fmaxf(cA1[2], cA1[3]), fmaxf(cB1[2], cB1[3]));
                ushort_t* po = pl + (py * 26 + px0) * ICP;
                po[lr]            = f2h(fmaxf(u0 + bv0, 0.0f));
                po[16 + lr]       = f2h(fmaxf(v0 + bv1, 0.0f));
                po[ICP + lr]      = f2h(fmaxf(u1 + bv0, 0.0f));
                po[ICP + 16 + lr] = f2h(fmaxf(v1 + bv1, 0.0f));
            }
        }
    }

    __syncthreads();

    // ================= phase B: conv2 via MFMA (3 row-chunks) =================
    int prow  = wid >> 1;
    int nhalf = wid & 1;
    const ushort_t* wb = wr + (size_t)(nhalf * 32 + lr) * 288 + quad * 8;

    int ocl = lane & 31;
    int pxh = lane >> 5;
    int oc  = nhalf * 32 + ocl;
    float bv = bias2[oc];
    ushort_t* scr = smem + PL_USH + wid * (32 * SCR);

    for (int cc = 0; cc < 3; ++cc) {
        int ebase[3];
#pragma unroll
        for (int t = 0; t < 3; ++t) {
            int m  = t * 16 + lr;
            int yl = m / 24;
            int xx = m - yl * 24;
            ebase[t] = ((8 * cc + 2 * prow + yl) * 26 + xx) * ICP + quad * 8;
        }

        f32x4 acc[3][2];
#pragma unroll
        for (int t = 0; t < 3; ++t)
#pragma unroll
            for (int n = 0; n < 2; ++n) acc[t][n] = (f32x4){0.f, 0.f, 0.f, 0.f};

#pragma unroll
        for (int tap = 0; tap < 9; ++tap) {
            int ky = tap / 3, kx = tap % 3;
            int koff = (ky * 26 + kx) * ICP;
            f16x8 a[3];
#pragma unroll
            for (int t = 0; t < 3; ++t) {
                union { ushort4v s[2]; f16x8 v; } u;
                u.s[0] = *reinterpret_cast<const ushort4v*>(&pl[ebase[t] + koff]);
                u.s[1] = *reinterpret_cast<const ushort4v*>(&pl[ebase[t] + koff + 4]);
                a[t] = u.v;
            }
            f16x8 bf[2];
#pragma unroll
            for (int n = 0; n < 2; ++n)
                bf[n] = *reinterpret_cast<const f16x8*>(wb + (size_t)n * 16 * 288 + tap * 32);
#pragma unroll
            for (int t = 0; t < 3; ++t)
#pragma unroll
                for (int n = 0; n < 2; ++n)
                    acc[t][n] = __builtin_amdgcn_mfma_f32_16x16x32_f16(a[t], bf[n], acc[t][n], 0, 0, 0);
        }

#pragma unroll
        for (int t = 0; t < 3; ++t)
#pragma unroll
            for (int n = 0; n < 2; ++n) {
                int wocl = n * 16 + lr;
                int i0 = t * 8 + quad * 2;
                float v0 = fmaxf(acc[t][n][0], acc[t][n][1]);
                float v1 = fmaxf(acc[t][n][2], acc[t][n][3]);
                union { ushort_t u2[2]; unsigned w; } pk;
                pk.u2[0] = f2h(v0); pk.u2[1] = f2h(v1);
                *reinterpret_cast<unsigned*>(&scr[wocl * SCR + i0]) = pk.w;
            }
        asm volatile("s_waitcnt lgkmcnt(0)" ::: "memory");

        const ushort_t* row = scr + ocl * SCR;
        int py = cc * 4 + prow;
        ushort_t* po = pool2cl + ((size_t)b * 144 + py * 12) * 64 + oc;
#pragma unroll
        for (int j = 0; j < 6; ++j) {
            int px = pxh * 6 + j;
            float r0 = h2f(row[px]);
            float r1 = h2f(row[px + 12]);
            po[px * 64] = f2h(fmaxf(fmaxf(r0, r1) + bv, 0.0f));
        }
        asm volatile("s_waitcnt lgkmcnt(0)" ::: "memory");
    }
}

// ---------------- k3: fc1 fp16 MFMA (mt-paired) + distributed fc2 finisher ----------------
// 256 blocks x 256 thr = 1024 waves: (nt 4) x (ks 16) x (mt 16, 32 rows each).
// Block bk covers one (mt=bk>>4, ks=bk&15), nt=0..3. The 16 blocks sharing mt
// complete C rows [32mt,32mt+32); last arriver runs fc2 for those 32 rows.
__global__ __launch_bounds__(256) void fc1_mfma(const ushort_t* __restrict__ A,
                                                const ushort_t* __restrict__ W,
                                                float* __restrict__ C,
                                                int* __restrict__ counters,
                                                const float* __restrict__ fb1,
                                                const float* __restrict__ w2,
                                                const float* __restrict__ fb2,
                                                float* __restrict__ out) {
    __shared__ float w2s[10 * 128];          // 5 KB
    __shared__ float part[8][32][10];        // 10 KB
    __shared__ int lastFlag;
    int tid = threadIdx.x;
    int lane = tid & 63, wid = tid >> 6;
    int lr = lane & 15, quad = lane >> 4;
    int w  = blockIdx.x * 4 + wid;     // 0..1023
    int nt = w & 3;
    int ks = (w >> 2) & 15;
    int mt = w >> 6;                   // 0..15, block-uniform

    int m0 = mt * 32;
    int n0 = nt * 32;
    int k0 = ks * 576 + quad * 8;
    const ushort_t* a0  = A + (size_t)(m0 + lr) * 9216 + k0;
    const ushort_t* a1  = a0 + (size_t)16 * 9216;
    const ushort_t* b0  = W + (size_t)(n0 + lr) * 9216 + k0;
    const ushort_t* b1p = b0 + (size_t)16 * 9216;

    f32x4 acc00 = (f32x4){0.f,0.f,0.f,0.f};
    f32x4 acc01 = acc00, acc10 = acc00, acc11 = acc00;

#pragma unroll
    for (int kk = 0; kk < 18; ++kk) {
        f16x8 av0 = *reinterpret_cast<const f16x8*>(a0 + kk * 32);
        f16x8 av1 = *reinterpret_cast<const f16x8*>(a1 + kk * 32);
        f16x8 bv0 = *reinterpret_cast<const f16x8*>(b0 + kk * 32);
        f16x8 bv1 = *reinterpret_cast<const f16x8*>(b1p + kk * 32);
        acc00 = __builtin_amdgcn_mfma_f32_16x16x32_f16(av0, bv0, acc00, 0, 0, 0);
        acc01 = __builtin_amdgcn_mfma_f32_16x16x32_f16(av0, bv1, acc01, 0, 0, 0);
        acc10 = __builtin_amdgcn_mfma_f32_16x16x32_f16(av1, bv0, acc10, 0, 0, 0);
        acc11 = __builtin_amdgcn_mfma_f32_16x16x32_f16(av1, bv1, acc11, 0, 0, 0);
    }

    int crow = m0 + quad * 4;
#pragma unroll
    for (int r = 0; r < 4; ++r) {
        atomicAdd(&C[(size_t)(crow + r) * 128 + n0 + lr],           acc00[r]);
        atomicAdd(&C[(size_t)(crow + r) * 128 + n0 + 16 + lr],      acc01[r]);
        atomicAdd(&C[(size_t)(crow + r + 16) * 128 + n0 + lr],      acc10[r]);
        atomicAdd(&C[(size_t)(crow + r + 16) * 128 + n0 + 16 + lr], acc11[r]);
    }

    // ---- distributed finisher: last of the 16 blocks sharing mt does fc2 ----
    __threadfence();               // make this block's C atomics device-visible
    __syncthreads();
    if (tid == 0) lastFlag = (atomicAdd(&counters[mt], 1) == 15);
    __syncthreads();
    if (!lastFlag) return;

    for (int i = tid; i < 1280; i += 256) w2s[i] = w2[i];
    __syncthreads();

    {
        int row   = tid & 31;              // 0..31 local row
        int slice = tid >> 5;              // 0..7, 16 k each
        const float* crp = C + (size_t)(m0 + row) * 128 + slice * 16;
        float pacc[10];
#pragma unroll
        for (int o = 0; o < 10; ++o) pacc[o] = 0.f;
#pragma unroll
        for (int j = 0; j < 16; ++j) {
            float cv = __hip_atomic_load(&crp[j], __ATOMIC_RELAXED,
                                         __HIP_MEMORY_SCOPE_AGENT);
            float hv = fmaxf(cv + fb1[slice * 16 + j], 0.0f);
#pragma unroll
            for (int o = 0; o < 10; ++o) pacc[o] += hv * w2s[o * 128 + slice * 16 + j];
        }
#pragma unroll
        for (int o = 0; o < 10; ++o) part[slice][row][o] = pacc[o];
    }
    __syncthreads();

    for (int q = tid; q < 320; q += 256) {
        int row = q / 10, o = q - row * 10;
        float s = 0.f;
#pragma unroll
        for (int sl = 0; sl < 8; ++sl) s += part[sl][row][o];
        out[(m0 + row) * 10 + o] = s + fb2[o];
    }
}

extern "C" void kernel_launch(void* const* d_in, const int* in_sizes, int n_in,
                              void* d_out, int out_size, void* d_ws, size_t ws_size,
                              hipStream_t stream) {
    const float* x       = (const float*)d_in[0];
    const float* conv1_w = (const float*)d_in[1];
    const float* conv1_b = (const float*)d_in[2];
    const float* conv2_w = (const float*)d_in[3];
    const float* conv2_b = (const float*)d_in[4];
    const float* fc1_w   = (const float*)d_in[5];
    const float* fc1_b   = (const float*)d_in[6];
    const float* fc2_w   = (const float*)d_in[7];
    const float* fc2_b   = (const float*)d_in[8];
    float* out = (float*)d_out;

    char* ws = (char*)d_ws;
    ushort_t* wr = (ushort_t*)ws;
    ws += N_WR * sizeof(ushort_t) + 128;
    ushort_t* wfb = (ushort_t*)ws;
    ws += (size_t)128 * 9216 * sizeof(ushort_t) + 128;
    ushort_t* pool2cl = (ushort_t*)ws;
    ws += (size_t)B * P2SZ * sizeof(ushort_t) + 128;
    float* C = (float*)ws;                       // 512*128 floats + 16 counters
    int* counters = (int*)(C + 512 * 128);
    ws += ((size_t)512 * 128 + 16) * sizeof(float) + 128;

    prep<<<WR_BLOCKS + TR_BLOCKS, 256, 0, stream>>>(conv2_w, fc1_w, wr, wfb, C);
    conv12<<<B, 512, 0, stream>>>(x, conv1_w, conv1_b, wr, conv2_b, pool2cl);
    fc1_mfma<<<FC1_BLOCKS, 256, 0, stream>>>(pool2cl, wfb, C, counters,
                                             fc1_b, fc2_w, fc2_b, out);
}

// Round 11
// 111.925 us; speedup vs baseline: 1.1165x; 1.1165x over previous
//
#include <hip/hip_runtime.h>

// LNSNet forward, R23 = R21 exact revert (measured best: 112.47us).
// R22's distributed fc2 finisher regressed +12.5us: device-scope threadfence
// in all 256 blocks + finisher LDS/VGPR overhead outweighs the saved launch.
// CLOSED PATHS (all measured): fc2-in-fc1 fusion (R16 monolithic +77, R20
// single-block tail +41, R22 distributed tail +12.5); conv12 half-split
// (R18 +3.7, VGPR-occupancy-neutral); atomic-vs-Cpart fc1 (R19b wash).
// KEPT WINS: conv1+conv2 LDS fusion (R15 -7.3), barrier relaxation +
// vectorized staging (R17 -4.8), fc1 mt-pairing (R21 -2.0).
// Budget: fills ~82us (harness, uncontrollable) | conv12 ~12 | fc1 ~5 |
// fc2k ~4 | prep ~3 | gaps ~5.

#define B 512
#define POS 676
#define ICP 36
#define P2SZ (64*12*12)
#define SCR 26
#define IMS 58                  // LDS image row stride (ushorts), odd dwords
#define IMCOPY (54 * IMS)       // 3132 ushorts per copy
#define PL_USH (POS * ICP)      // 24336 ushorts: pool1 in LDS
#define SCRATCH_USH 6656        // max(image 2*IMCOPY+96=6360, scr 8*832=6656)

typedef unsigned short ushort_t;
typedef ushort_t ushort4v __attribute__((ext_vector_type(4)));
typedef _Float16 f16x8 __attribute__((ext_vector_type(8)));
typedef float f32x4 __attribute__((ext_vector_type(4)));

__device__ __forceinline__ ushort_t f2h(float f) {
    union { _Float16 h; ushort_t u; } a; a.h = (_Float16)f; return a.u;
}
__device__ __forceinline__ float h2f(ushort_t u) {
    union { ushort_t u; _Float16 h; } a; a.u = u; return (float)a.h;
}

#define N_WR (64 * 9 * 32)
#define WR_BLOCKS 72
#define TR_BLOCKS 128
#define PREP_THREADS ((WR_BLOCKS + TR_BLOCKS) * 256)
#define FC1_BLOCKS 256

// ---------------- k0: conv2-weight reorder + fc1-W transpose + C zero ----------------
__global__ __launch_bounds__(256) void prep(const float* __restrict__ c2w,
                                            const float* __restrict__ f1w,
                                            ushort_t* __restrict__ wr,
                                            ushort_t* __restrict__ wfb,
                                            float* __restrict__ C) {
    __shared__ float tr[64 * 145];          // 37,120 B (transpose branch only)
    int blk = blockIdx.x;
    int tid = threadIdx.x;

    // zero the fc1 atomic-accumulator (512*128 floats over 51200 threads)
    int gtid = blk * 256 + tid;
    for (int i = gtid; i < 512 * 128; i += PREP_THREADS) C[i] = 0.0f;

    if (blk < WR_BLOCKS) {
        int t = blk * 256 + tid;
        int ic  = t & 31;
        int tap = (t >> 5) % 9;
        int oc  = t / 288;
        wr[t] = f2h(c2w[oc * 288 + ic * 9 + tap]);
        return;
    }
    // ---- fc1 W transpose via LDS tile ----
    int n = blk - WR_BLOCKS;
    const float* src = f1w + (size_t)n * 9216;
#pragma unroll
    for (int i = 0; i < 36; ++i) {
        int idx = i * 256 + tid;
        int oc = idx / 144, pos = idx - oc * 144;
        tr[oc * 145 + pos] = src[idx];
    }
    __syncthreads();
    ushort_t* dst = wfb + (size_t)n * 9216;
#pragma unroll
    for (int i = 0; i < 36; ++i) {
        int idx = i * 256 + tid;
        int pos = idx >> 6, oc = idx & 63;
        dst[idx] = f2h(tr[oc * 145 + pos]);
    }
}

// ---------------- k12: fused conv1 -> pool1(LDS) -> conv2 -> pool2 (R17 form) ----------------
__global__ __launch_bounds__(512, 4) void conv12(const float* __restrict__ x,
                                                 const float* __restrict__ w1,
                                                 const float* __restrict__ bias1,
                                                 const ushort_t* __restrict__ wr,
                                                 const float* __restrict__ bias2,
                                                 ushort_t* __restrict__ pool2cl) {
    __shared__ ushort_t smem[PL_USH + SCRATCH_USH];   // 61,984 B -> 2 blocks/CU
    ushort_t* pl  = smem;            // pool1: [676 pos][36], cols 0..31 used
    ushort_t* img = smem + PL_USH;   // phase A image (2 col-shifted copies)

    int b   = blockIdx.x;
    int tid = threadIdx.x;
    int lane = tid & 63, wid = tid >> 6;        // 8 waves
    int quad = lane >> 4, lr = lane & 15;

    // ================= phase A: conv1 via MFMA =================
    for (int i = tid; i < 54; i += 512) {
        ushort_t* r0 = img + i * IMS;
        r0[54] = 0; r0[55] = 0; r0[56] = 0; r0[57] = 0;
        ushort_t* r1 = img + IMCOPY + i * IMS;
        r1[53] = 0; r1[54] = 0; r1[55] = 0; r1[56] = 0; r1[57] = 0;
    }
    if (tid < 96) img[2 * IMCOPY + tid] = 0;

    // stage image b: fp32 -> fp16 via float4 (2916 = 729 vec4; c==52 straddles)
    const float* xim = x + (size_t)b * 2916;
    for (int i = tid; i < 729; i += 512) {
        int e = i * 4;
        int r = e / 54, c = e - r * 54;        // c even
        float4 xv = *reinterpret_cast<const float4*>(&xim[e]);
        ushort_t h0 = f2h(xv.x), h1 = f2h(xv.y), h2 = f2h(xv.z), h3 = f2h(xv.w);
        if (c <= 50) {
            ushort_t* p0 = &img[r * IMS + c];
            p0[0] = h0; p0[1] = h1; p0[2] = h2; p0[3] = h3;
            ushort_t* p1 = &img[IMCOPY + r * IMS + c - 1];
            if (c > 0) p1[0] = h0;
            p1[1] = h1; p1[2] = h2; p1[3] = h3;
        } else {   // c == 52
            img[r * IMS + 52] = h0;
            img[r * IMS + 53] = h1;
            img[(r + 1) * IMS + 0] = h2;
            img[(r + 1) * IMS + 1] = h3;
            img[IMCOPY + r * IMS + 51] = h0;
            img[IMCOPY + r * IMS + 52] = h1;
            img[IMCOPY + (r + 1) * IMS + 0] = h3;
        }
    }

    // B-frags: w1[oc][ky=quad][kx=0..2], zeros elsewhere (incl quad==3)
    f16x8 bfrag[2];
#pragma unroll
    for (int n = 0; n < 2; ++n) {
        union { ushort_t u[8]; f16x8 v; } bu;
#pragma unroll
        for (int j = 0; j < 8; ++j) bu.u[j] = 0;
        if (quad < 3) {
            const float* wp = w1 + (n * 16 + lr) * 9 + quad * 3;
            bu.u[0] = f2h(wp[0]);
            bu.u[1] = f2h(wp[1]);
            bu.u[2] = f2h(wp[2]);
        }
        bfrag[n] = bu.v;
    }
    float bv0 = bias1[lr], bv1 = bias1[16 + lr];

    __syncthreads();

    int cbase = (lr & 1) ? (IMCOPY + lr - 1) : lr;

    for (int it = 0; it < 4; ++it) {
        int py = wid + it * 8;
        if (py >= 26) break;
        int y0 = 2 * py;
#pragma unroll
        for (int t = 0; t < 4; ++t) {
            int x0 = t * 16;
            int off0 = cbase + x0 + (y0 + quad) * IMS;
            int off1 = off0 + IMS;
            union { unsigned d[4]; f16x8 v; } a0, a1;
            a0.d[0] = *reinterpret_cast<const unsigned*>(&img[off0]);
            a0.d[1] = *reinterpret_cast<const unsigned*>(&img[off0 + 2]);
            a0.d[2] = a0.d[0]; a0.d[3] = a0.d[1];
            a1.d[0] = *reinterpret_cast<const unsigned*>(&img[off1]);
            a1.d[1] = *reinterpret_cast<const unsigned*>(&img[off1 + 2]);
            a1.d[2] = a1.d[0]; a1.d[3] = a1.d[1];

            f32x4 cA0 = (f32x4){0.f,0.f,0.f,0.f}, cA1 = cA0, cB0 = cA0, cB1 = cA0;
            cA0 = __builtin_amdgcn_mfma_f32_16x16x32_f16(a0.v, bfrag[0], cA0, 0, 0, 0);
            cA1 = __builtin_amdgcn_mfma_f32_16x16x32_f16(a0.v, bfrag[1], cA1, 0, 0, 0);
            cB0 = __builtin_amdgcn_mfma_f32_16x16x32_f16(a1.v, bfrag[0], cB0, 0, 0, 0);
            cB1 = __builtin_amdgcn_mfma_f32_16x16x32_f16(a1.v, bfrag[1], cB1, 0, 0, 0);

            if (t < 3 || quad == 0) {
                int px0 = t * 8 + quad * 2;
                float u0 = fmaxf(fmaxf(cA0[0], cA0[1]), fmaxf(cB0[0], cB0[1]));
                float u1 = fmaxf(fmaxf(cA0[2], cA0[3]), fmaxf(cB0[2], cB0[3]));
                float v0 = fmaxf(fmaxf(cA1[0], cA1[1]), fmaxf(cB1[0], cB1[1]));
                float v1 = fmaxf(fmaxf(cA1[2], cA1[3]), fmaxf(cB1[2], cB1[3]));
                ushort_t* po = pl + (py * 26 + px0) * ICP;
                po[lr]            = f2h(fmaxf(u0 + bv0, 0.0f));
                po[16 + lr]       = f2h(fmaxf(v0 + bv1, 0.0f));
                po[ICP + lr]      = f2h(fmaxf(u1 + bv0, 0.0f));
                po[ICP + 16 + lr] = f2h(fmaxf(v1 + bv1, 0.0f));
            }
        }
    }

    __syncthreads();

    // ================= phase B: conv2 via MFMA (3 row-chunks) =================
    int prow  = wid >> 1;
    int nhalf = wid & 1;
    const ushort_t* wb = wr + (size_t)(nhalf * 32 + lr) * 288 + quad * 8;

    int ocl = lane & 31;
    int pxh = lane >> 5;
    int oc  = nhalf * 32 + ocl;
    float bv = bias2[oc];
    ushort_t* scr = smem + PL_USH + wid * (32 * SCR);

    for (int cc = 0; cc < 3; ++cc) {
        int ebase[3];
#pragma unroll
        for (int t = 0; t < 3; ++t) {
            int m  = t * 16 + lr;
            int yl = m / 24;
            int xx = m - yl * 24;
            ebase[t] = ((8 * cc + 2 * prow + yl) * 26 + xx) * ICP + quad * 8;
        }

        f32x4 acc[3][2];
#pragma unroll
        for (int t = 0; t < 3; ++t)
#pragma unroll
            for (int n = 0; n < 2; ++n) acc[t][n] = (f32x4){0.f, 0.f, 0.f, 0.f};

#pragma unroll
        for (int tap = 0; tap < 9; ++tap) {
            int ky = tap / 3, kx = tap % 3;
            int koff = (ky * 26 + kx) * ICP;
            f16x8 a[3];
#pragma unroll
            for (int t = 0; t < 3; ++t) {
                union { ushort4v s[2]; f16x8 v; } u;
                u.s[0] = *reinterpret_cast<const ushort4v*>(&pl[ebase[t] + koff]);
                u.s[1] = *reinterpret_cast<const ushort4v*>(&pl[ebase[t] + koff + 4]);
                a[t] = u.v;
            }
            f16x8 bf[2];
#pragma unroll
            for (int n = 0; n < 2; ++n)
                bf[n] = *reinterpret_cast<const f16x8*>(wb + (size_t)n * 16 * 288 + tap * 32);
#pragma unroll
            for (int t = 0; t < 3; ++t)
#pragma unroll
                for (int n = 0; n < 2; ++n)
                    acc[t][n] = __builtin_amdgcn_mfma_f32_16x16x32_f16(a[t], bf[n], acc[t][n], 0, 0, 0);
        }

#pragma unroll
        for (int t = 0; t < 3; ++t)
#pragma unroll
            for (int n = 0; n < 2; ++n) {
                int wocl = n * 16 + lr;
                int i0 = t * 8 + quad * 2;
                float v0 = fmaxf(acc[t][n][0], acc[t][n][1]);
                float v1 = fmaxf(acc[t][n][2], acc[t][n][3]);
                union { ushort_t u2[2]; unsigned w; } pk;
                pk.u2[0] = f2h(v0); pk.u2[1] = f2h(v1);
                *reinterpret_cast<unsigned*>(&scr[wocl * SCR + i0]) = pk.w;
            }
        asm volatile("s_waitcnt lgkmcnt(0)" ::: "memory");

        const ushort_t* row = scr + ocl * SCR;
        int py = cc * 4 + prow;
        ushort_t* po = pool2cl + ((size_t)b * 144 + py * 12) * 64 + oc;
#pragma unroll
        for (int j = 0; j < 6; ++j) {
            int px = pxh * 6 + j;
            float r0 = h2f(row[px]);
            float r1 = h2f(row[px + 12]);
            po[px * 64] = f2h(fmaxf(fmaxf(r0, r1) + bv, 0.0f));
        }
        asm volatile("s_waitcnt lgkmcnt(0)" ::: "memory");
    }
}

// ---------------- k3: fc1 fp16 MFMA (mt-paired), atomic accumulate ----------------
// 256 blocks x 256 thr = 1024 waves: (nt 4) x (ks 16) x (mt 16, 32 rows each).
// Per wave: 18 kk x {2 A-frags share 2 B-frags, 4 MFMA}. No tail (R20/R22 lesson).
__global__ __launch_bounds__(256) void fc1_mfma(const ushort_t* __restrict__ A,
                                                const ushort_t* __restrict__ W,
                                                float* __restrict__ C) {
    int tid = threadIdx.x;
    int lane = tid & 63, wid = tid >> 6;
    int lr = lane & 15, quad = lane >> 4;
    int w  = blockIdx.x * 4 + wid;     // 0..1023
    int nt = w & 3;
    int ks = (w >> 2) & 15;
    int mt = w >> 6;                   // 0..15

    int m0 = mt * 32;
    int n0 = nt * 32;
    int k0 = ks * 576 + quad * 8;
    const ushort_t* a0  = A + (size_t)(m0 + lr) * 9216 + k0;
    const ushort_t* a1  = a0 + (size_t)16 * 9216;
    const ushort_t* b0  = W + (size_t)(n0 + lr) * 9216 + k0;
    const ushort_t* b1p = b0 + (size_t)16 * 9216;

    f32x4 acc00 = (f32x4){0.f,0.f,0.f,0.f};
    f32x4 acc01 = acc00, acc10 = acc00, acc11 = acc00;

#pragma unroll
    for (int kk = 0; kk < 18; ++kk) {
        f16x8 av0 = *reinterpret_cast<const f16x8*>(a0 + kk * 32);
        f16x8 av1 = *reinterpret_cast<const f16x8*>(a1 + kk * 32);
        f16x8 bv0 = *reinterpret_cast<const f16x8*>(b0 + kk * 32);
        f16x8 bv1 = *reinterpret_cast<const f16x8*>(b1p + kk * 32);
        acc00 = __builtin_amdgcn_mfma_f32_16x16x32_f16(av0, bv0, acc00, 0, 0, 0);
        acc01 = __builtin_amdgcn_mfma_f32_16x16x32_f16(av0, bv1, acc01, 0, 0, 0);
        acc10 = __builtin_amdgcn_mfma_f32_16x16x32_f16(av1, bv0, acc10, 0, 0, 0);
        acc11 = __builtin_amdgcn_mfma_f32_16x16x32_f16(av1, bv1, acc11, 0, 0, 0);
    }

    int crow = m0 + quad * 4;
#pragma unroll
    for (int r = 0; r < 4; ++r) {
        atomicAdd(&C[(size_t)(crow + r) * 128 + n0 + lr],           acc00[r]);
        atomicAdd(&C[(size_t)(crow + r) * 128 + n0 + 16 + lr],      acc01[r]);
        atomicAdd(&C[(size_t)(crow + r + 16) * 128 + n0 + lr],      acc10[r]);
        atomicAdd(&C[(size_t)(crow + r + 16) * 128 + n0 + 16 + lr], acc11[r]);
    }
}

// ---------------- k4: bias + relu + fc2 (C already summed) ----------------
__global__ __launch_bounds__(256) void fc2k(const float* __restrict__ C,
                                            const float* __restrict__ b1,
                                            const float* __restrict__ w2,
                                            const float* __restrict__ b2,
                                            float* __restrict__ out) {
    __shared__ float h[2][128];
    int half = threadIdx.x >> 7;
    int k = threadIdx.x & 127;
    int b = blockIdx.x * 2 + half;
    float s = C[(size_t)b * 128 + k];
    h[half][k] = fmaxf(s + b1[k], 0.0f);
    __syncthreads();
    if (k < 10) {
        const float* wp = w2 + k * 128;
        float acc = 0.f;
#pragma unroll 8
        for (int j = 0; j < 128; ++j) acc += h[half][j] * wp[j];
        out[b * 10 + k] = acc + b2[k];
    }
}

extern "C" void kernel_launch(void* const* d_in, const int* in_sizes, int n_in,
                              void* d_out, int out_size, void* d_ws, size_t ws_size,
                              hipStream_t stream) {
    const float* x       = (const float*)d_in[0];
    const float* conv1_w = (const float*)d_in[1];
    const float* conv1_b = (const float*)d_in[2];
    const float* conv2_w = (const float*)d_in[3];
    const float* conv2_b = (const float*)d_in[4];
    const float* fc1_w   = (const float*)d_in[5];
    const float* fc1_b   = (const float*)d_in[6];
    const float* fc2_w   = (const float*)d_in[7];
    const float* fc2_b   = (const float*)d_in[8];
    float* out = (float*)d_out;

    char* ws = (char*)d_ws;
    ushort_t* wr = (ushort_t*)ws;
    ws += N_WR * sizeof(ushort_t) + 128;
    ushort_t* wfb = (ushort_t*)ws;
    ws += (size_t)128 * 9216 * sizeof(ushort_t) + 128;
    ushort_t* pool2cl = (ushort_t*)ws;
    ws += (size_t)B * P2SZ * sizeof(ushort_t) + 128;
    float* C = (float*)ws;
    ws += (size_t)512 * 128 * sizeof(float) + 128;

    prep<<<WR_BLOCKS + TR_BLOCKS, 256, 0, stream>>>(conv2_w, fc1_w, wr, wfb, C);
    conv12<<<B, 512, 0, stream>>>(x, conv1_w, conv1_b, wr, conv2_b, pool2cl);
    fc1_mfma<<<FC1_BLOCKS, 256, 0, stream>>>(pool2cl, wfb, C);
    fc2k<<<256, 256, 0, stream>>>(C, fc1_b, fc2_w, fc2_b, out);
}